// Round 7
// baseline (1583.390 us; speedup 1.0000x reference)
//
#include <hip/hip_runtime.h>

// Problem constants (MyHead_67242007986918)
#define NPTS 80000      // B*NP
#define NPER 20000      // NP per batch
#define CDIM 256
#define NNB  16
#define NKP  15
#define NCLS 17
#define GSH  32
#define GSW  128

typedef __bf16 bf16x8 __attribute__((ext_vector_type(8)));
typedef float  f32x4  __attribute__((ext_vector_type(4)));
typedef float  f32x2  __attribute__((ext_vector_type(2)));

__device__ __forceinline__ float bf2f_lo(unsigned int u){ return __uint_as_float(u << 16); }
__device__ __forceinline__ float bf2f_hi(unsigned int u){ return __uint_as_float(u & 0xFFFF0000u); }
__device__ __forceinline__ unsigned short f2bf(float f){
    unsigned int u = __float_as_uint(f);
    u = u + 0x7FFFu + ((u >> 16) & 1u);     // RNE
    return (unsigned short)(u >> 16);
}
__device__ __forceinline__ unsigned int pack2(float a, float b){
    return (unsigned int)f2bf(a) | ((unsigned int)f2bf(b) << 16);
}

// async global->LDS, 16B per lane; lds dest = wave-uniform base + lane*16
#define GLD_LDS16(gsrc, ldst) \
    __builtin_amdgcn_global_load_lds((const __attribute__((address_space(1))) unsigned int*)(gsrc), \
                                     (__attribute__((address_space(3))) unsigned int*)(ldst), 16, 0, 0)

// ---------------- ws layout (R1-verified footprint, 124,848,128 B) ----------------
// feats  bf16 [NPTS][256]            :      0 .. 40,960,000
// kpwS   bf16 swizzled B (983040 el) : 40,960,000 .. 42,926,080
// outbuf f32  [NPTS][256]            : 42,926,080 .. 124,846,080
// stats  f32  [512] (sum, sumsq)     : 124,846,080 .. 124,848,128
#define WS_KPWT   40960000
#define WS_OUT    42926080
#define WS_STATS  124846080
#define WS_NEED   124848128

// swizzled B geometry: window (chunk c, pair P) holds K=32 = {k=2P+kwin} x {16 ch}
//  P<7 : block 8192 elems at (c*7+P)*8192 ; elem = (ct*64 + q*16+m)*8 + j
//  P==7: block 4096 elems at 917504 + c*4096 (kwin0=k14 only); elem = (ct*32 + (q&1)*16+m)*8 + j
#define B7_BASE 917504

// Fused rearrange + bilinear grid-sample (border pad, align_corners=False) -> bf16 feats
__global__ __launch_bounds__(256) void gs_kernel(
    const float* __restrict__ x, const float* __restrict__ px,
    const float* __restrict__ py, unsigned short* __restrict__ feats)
{
    int gid = blockIdx.x * 256 + threadIdx.x;           // 80000*64 threads
    int n = gid >> 6;
    if (n >= NPTS) return;
    int c0 = (gid & 63) << 2;
    int b = n / NPER;
    float ix = fminf(fmaxf(((px[n] + 1.f) * (float)GSW - 1.f) * 0.5f, 0.f), (float)(GSW - 1));
    float iy = fminf(fmaxf(((py[n] + 1.f) * (float)GSH - 1.f) * 0.5f, 0.f), (float)(GSH - 1));
    float x0f = floorf(ix), y0f = floorf(iy);
    float wx = ix - x0f, wy = iy - y0f;
    int x0 = (int)x0f, y0 = (int)y0f;
    int x1 = min(x0 + 1, GSW - 1), y1 = min(y0 + 1, GSH - 1);
    const float* base = x + (size_t)b * (GSH * GSW * CDIM);
    float4 v00 = *(const float4*)(base + ((size_t)(y0 * GSW + x0)) * CDIM + c0);
    float4 v01 = *(const float4*)(base + ((size_t)(y0 * GSW + x1)) * CDIM + c0);
    float4 v10 = *(const float4*)(base + ((size_t)(y1 * GSW + x0)) * CDIM + c0);
    float4 v11 = *(const float4*)(base + ((size_t)(y1 * GSW + x1)) * CDIM + c0);
    float w00 = (1.f - wx) * (1.f - wy), w01 = wx * (1.f - wy);
    float w10 = (1.f - wx) * wy,         w11 = wx * wy;
    float r0 = v00.x * w00 + v01.x * w01 + v10.x * w10 + v11.x * w11;
    float r1 = v00.y * w00 + v01.y * w01 + v10.y * w10 + v11.y * w11;
    float r2 = v00.z * w00 + v01.z * w01 + v10.z * w10 + v11.z * w11;
    float r3 = v00.w * w00 + v01.w * w01 + v10.w * w10 + v11.w * w11;
    ushort4 o; o.x = f2bf(r0); o.y = f2bf(r1); o.z = f2bf(r2); o.w = f2bf(r3);
    *(ushort4*)(feats + (size_t)n * CDIM + c0) = o;
}

// kp_weights [k][c][d] f32 -> swizzled MFMA-B-fragment order; block 0 also zeroes stats.
__global__ __launch_bounds__(256) void wt_kernel(
    const float* __restrict__ kpw, unsigned short* __restrict__ kpwS, float* __restrict__ stats)
{
    if (blockIdx.x == 0){ stats[threadIdx.x] = 0.f; stats[256 + threadIdx.x] = 0.f; }
    int gid = blockIdx.x * 256 + threadIdx.x;           // 15*65536 = 983,040 -> 3840 blocks
    int k = gid >> 16;
    int c = (gid >> 8) & 255;
    int d = gid & 255;
    unsigned short v = f2bf(kpw[gid]);
    int pair = k >> 1, kwin = k & 1, chunk = c >> 4, cl = c & 15;
    int kap = kwin * 16 + cl;                           // K-elem within window
    int q = kap >> 3, j = kap & 7;
    int m = d & 15, ctg = d >> 4;
    int idx;
    if (pair < 7) idx = (chunk * 7 + pair) * 8192 + (ctg * 64 + q * 16 + m) * 8 + j;
    else          idx = B7_BASE + chunk * 4096 + (ctg * 32 + q * 16 + m) * 8 + j;  // k=14 -> kwin0
    kpwS[idx] = v;
}

// Fused KPConv — BARRIER-FREE. Block = 1 wave (64 thr), 16-pt tile, all 256 out-ch.
// Wave-private s_fN slab (8KB LDS), wf routed to MFMA-A via quad shuffles (no s_wf).
// Grid 5024, XCD-swizzled: t = (bid%8)*628 + bid/8 -> each XCD works one half-batch.
__global__ __launch_bounds__(64, 3) void kpconv_kernel(
    const unsigned short* __restrict__ feats,
    const unsigned short* __restrict__ kpwS,
    const int*   __restrict__ pknn,
    const float* __restrict__ pxyz,
    const float* __restrict__ kp_pts,
    float* __restrict__ outbuf,
    float* __restrict__ stats)
{
    __shared__ unsigned short s_fN[4096];    // 8KB [a16][p16][c16]

    int bid = blockIdx.x;
    int t = (bid & 7) * 628 + (bid >> 3);
    if (t >= 5000) return;
    int n0 = t * 16;
    int b = n0 / NPER;                       // uniform: 16 | 20000, tiles never straddle

    int lane = threadIdx.x, m = lane & 15, q = lane >> 4, qh = q >> 1;
    int p1 = lane >> 2, cg = lane & 3;

    // ---- stager row bases: lane covers rows (a = 2i + (lane>>5), pl = (lane>>1)&15) ----
    int fb[8];
    {
        int pl = (lane >> 1) & 15;
        int n = n0 + pl;
#pragma unroll
        for (int i = 0; i < 8; i++){
            int a = 2 * i + (lane >> 5);
            fb[i] = (b * NPER + pknn[(size_t)n * NNB + a]) * CDIM + (lane & 1) * 8;
        }
    }

    // ---- w-phase: wreg[i][j] = bf16 pair (k=2j,2j+1) for a = 4*cg+i, point p1 ----
    unsigned int wreg[4][8];
    {
        int n = n0 + p1;
        float cx = pxyz[n * 3 + 0], cy = pxyz[n * 3 + 1], cz = pxyz[n * 3 + 2];
#pragma unroll
        for (int i = 0; i < 4; i++){
            int a = 4 * cg + i;
            int g = b * NPER + pknn[(size_t)n * NNB + a];
            float dx = pxyz[g * 3 + 0] - cx;
            float dy = pxyz[g * 3 + 1] - cy;
            float dz = pxyz[g * 3 + 2] - cz;
            float w[NKP];
#pragma unroll
            for (int k = 0; k < NKP; k++){
                float ex = dx - kp_pts[k * 3 + 0], ey = dy - kp_pts[k * 3 + 1], ez = dz - kp_pts[k * 3 + 2];
                w[k] = fmaxf(1.f - sqrtf(ex * ex + ey * ey + ez * ez) * (1.f / 1.2f), 0.f);
            }
#pragma unroll
            for (int j = 0; j < 7; j++) wreg[i][j] = pack2(w[2 * j], w[2 * j + 1]);
            wreg[i][7] = pack2(w[14], 0.f);  // k=15 phantom -> 0
        }
    }

    f32x4 acc[16];
#pragma unroll
    for (int i = 0; i < 16; i++){ acc[i][0]=0.f; acc[i][1]=0.f; acc[i][2]=0.f; acc[i][3]=0.f; }

    // ---- initial stage (chunk 0) ----
#pragma unroll
    for (int i = 0; i < 8; i++)
        GLD_LDS16(feats + (size_t)fb[i], (char*)s_fN + i * 1024);

    int qsrc = lane & ~3;                    // quad base (p1*4) for w shuffles
    int src0 = m * 4 + (q & 1) * 2;          // A-frag source lanes (point m, ch-half q&1)

    for (int c = 0; c < 16; c++){
        asm volatile("s_waitcnt vmcnt(0)" ::: "memory");   // stage(c) landed (wave-local)

#pragma unroll
        for (int kh = 0; kh < 2; kh++){
            // ---- phase 1: wf[8 kk][4 ch] over a = 0..15; w via quad shuffles ----
            f32x2 wf[8][2];
#pragma unroll
            for (int kk = 0; kk < 8; kk++){ wf[kk][0] = (f32x2)0.f; wf[kk][1] = (f32x2)0.f; }
#pragma unroll
            for (int a = 0; a < 16; a++){
                uint2 fv = *(const uint2*)&s_fN[(a * 16 + p1) * 16 + cg * 4];
                int src = qsrc | (a >> 2);
                unsigned int u0 = (unsigned int)__shfl((int)wreg[a & 3][4 * kh + 0], src);
                unsigned int u1 = (unsigned int)__shfl((int)wreg[a & 3][4 * kh + 1], src);
                unsigned int u2 = (unsigned int)__shfl((int)wreg[a & 3][4 * kh + 2], src);
                unsigned int u3 = (unsigned int)__shfl((int)wreg[a & 3][4 * kh + 3], src);
                f32x2 fa0; fa0[0] = bf2f_lo(fv.x); fa0[1] = bf2f_hi(fv.x);
                f32x2 fa1; fa1[0] = bf2f_lo(fv.y); fa1[1] = bf2f_hi(fv.y);
                float wk[8];
                wk[0]=bf2f_lo(u0); wk[1]=bf2f_hi(u0); wk[2]=bf2f_lo(u1); wk[3]=bf2f_hi(u1);
                wk[4]=bf2f_lo(u2); wk[5]=bf2f_hi(u2); wk[6]=bf2f_lo(u3); wk[7]=bf2f_hi(u3);
#pragma unroll
                for (int kk = 0; kk < 8; kk++){
                    f32x2 w2; w2[0] = wk[kk]; w2[1] = wk[kk];
                    wf[kk][0] = w2 * fa0 + wf[kk][0];
                    wf[kk][1] = w2 * fa1 + wf[kk][1];
                }
            }
            // ---- pack: po[kk] = 4 bf16 (ch 4cg..4cg+3) for k = 8kh+kk ----
            uint2 po[8];
#pragma unroll
            for (int kk = 0; kk < 8; kk++){
                po[kk].x = pack2(wf[kk][0][0], wf[kk][0][1]);
                po[kk].y = pack2(wf[kk][1][0], wf[kk][1][1]);
            }

            // kh1: s_fN(c) fully consumed -> issue next chunk's stage (overlaps MFMA)
            if (kh == 1){
                int cn = (c < 15) ? c + 1 : c;
#pragma unroll
                for (int i = 0; i < 8; i++)
                    GLD_LDS16(feats + (size_t)(fb[i] + cn * 16), (char*)s_fN + i * 1024);
            }

            // ---- phase 2: MFMA. A via quad shuffles (kk = 2Pl + qh), all 16 ct ----
#pragma unroll
            for (int Pl = 0; Pl < 4; Pl++){
                int a0 = __shfl((int)po[2 * Pl].x,     src0);
                int a1 = __shfl((int)po[2 * Pl].y,     src0);
                int a2 = __shfl((int)po[2 * Pl].x,     src0 + 1);
                int a3 = __shfl((int)po[2 * Pl].y,     src0 + 1);
                int b0 = __shfl((int)po[2 * Pl + 1].x, src0);
                int b1 = __shfl((int)po[2 * Pl + 1].y, src0);
                int b2 = __shfl((int)po[2 * Pl + 1].x, src0 + 1);
                int b3 = __shfl((int)po[2 * Pl + 1].y, src0 + 1);
                union { int u[4]; bf16x8 v; } A;
                A.u[0] = qh ? b0 : a0;
                A.u[1] = qh ? b1 : a1;
                A.u[2] = qh ? b2 : a2;
                A.u[3] = qh ? b3 : a3;
                int P = 4 * kh + Pl;
                const unsigned short* bb;
                int stride;
                if (P < 7){ bb = kpwS + (c * 7 + P) * 8192 + (q * 16 + m) * 8;        stride = 512; }
                else      { bb = kpwS + B7_BASE + c * 4096 + ((q & 1) * 16 + m) * 8;  stride = 256; }
#pragma unroll
                for (int ct = 0; ct < 16; ct++){
                    bf16x8 Bf = *(const bf16x8*)(bb + ct * stride);   // lane-contiguous 1KB burst
                    acc[ct] = __builtin_amdgcn_mfma_f32_16x16x32_bf16(A.v, Bf, acc[ct], 0, 0, 0);
                }
            }
        }
    }

    // ---- epilogue: store fp32, fold BN partial sums via atomics ----
#pragma unroll
    for (int ct = 0; ct < 16; ct++)
#pragma unroll
        for (int r = 0; r < 4; r++){
            int prow = 4 * q + r;            // C/D: row=(lane>>4)*4+r, col=lane&15
            outbuf[(size_t)(n0 + prow) * CDIM + ct * 16 + m] = acc[ct][r];
        }
#pragma unroll
    for (int ct = 0; ct < 16; ct++){
        float s1 = 0.f, s2 = 0.f;
#pragma unroll
        for (int r = 0; r < 4; r++){
            float v = acc[ct][r];
            s1 += v; s2 += v * v;
        }
        s1 += __shfl_xor(s1, 16); s1 += __shfl_xor(s1, 32);
        s2 += __shfl_xor(s2, 16); s2 += __shfl_xor(s2, 32);
        if (q == 0){
            atomicAdd(&stats[ct * 16 + m], s1);
            atomicAdd(&stats[256 + ct * 16 + m], s2);
        }
    }
}

// BN (batch stats) + ReLU + 1x1 conv head. 16 points per block.
__global__ __launch_bounds__(256) void head_kernel(
    const float* __restrict__ outbuf, const float* __restrict__ stats,
    const float* __restrict__ gamma,  const float* __restrict__ beta,
    const float* __restrict__ hw,     const float* __restrict__ hb,
    float* __restrict__ logits)
{
    __shared__ float s_h[16][256];
    int tid = threadIdx.x;
    int n0 = blockIdx.x * 16;
    int pt = tid >> 4, cgr = tid & 15;
    {
        int n = n0 + pt;
        const float invN = 1.f / (float)NPTS;
#pragma unroll
        for (int j = 0; j < 16; j += 4){
            int c = cgr * 16 + j;
            float4 v  = *(const float4*)(outbuf + (size_t)n * CDIM + c);
            float4 su = *(const float4*)(stats + c);
            float4 sq = *(const float4*)(stats + 256 + c);
            float4 ga = *(const float4*)(gamma + c);
            float4 be = *(const float4*)(beta + c);
            float mean, var;
            mean = su.x * invN; var = sq.x * invN - mean * mean;
            s_h[pt][c + 0] = fmaxf(ga.x * (v.x - mean) * rsqrtf(var + 1e-5f) + be.x, 0.f);
            mean = su.y * invN; var = sq.y * invN - mean * mean;
            s_h[pt][c + 1] = fmaxf(ga.y * (v.y - mean) * rsqrtf(var + 1e-5f) + be.y, 0.f);
            mean = su.z * invN; var = sq.z * invN - mean * mean;
            s_h[pt][c + 2] = fmaxf(ga.z * (v.z - mean) * rsqrtf(var + 1e-5f) + be.z, 0.f);
            mean = su.w * invN; var = sq.w * invN - mean * mean;
            s_h[pt][c + 3] = fmaxf(ga.w * (v.w - mean) * rsqrtf(var + 1e-5f) + be.w, 0.f);
        }
    }
    __syncthreads();
    for (int idx = tid; idx < 16 * NCLS; idx += 256){
        int pt2 = idx / NCLS, cls = idx - pt2 * NCLS;
        float acc = hb[cls];
#pragma unroll 8
        for (int c = 0; c < CDIM; c += 4){
            float4 h4 = *(const float4*)&s_h[pt2][c];
            float4 w4 = *(const float4*)(hw + (size_t)cls * CDIM + c);
            acc = fmaf(h4.x, w4.x, fmaf(h4.y, w4.y, fmaf(h4.z, w4.z, fmaf(h4.w, w4.w, acc))));
        }
        logits[(size_t)(n0 + pt2) * NCLS + cls] = acc;
    }
}

extern "C" void kernel_launch(void* const* d_in, const int* in_sizes, int n_in,
                              void* d_out, int out_size, void* d_ws, size_t ws_size,
                              hipStream_t stream)
{
    (void)in_sizes; (void)n_in; (void)out_size;
    if (ws_size < (size_t)WS_NEED) return;   // R1-verified footprint (119.06 MB)

    const float* x      = (const float*)d_in[0];
    // d_in[1] = skip  : dead code in reference
    const float* px     = (const float*)d_in[2];
    const float* py     = (const float*)d_in[3];
    const float* pxyz   = (const float*)d_in[4];
    const int*   pknn   = (const int*)  d_in[5];
    // d_in[6] = num_points : unused
    const float* kp_pts = (const float*)d_in[7];
    const float* kpw    = (const float*)d_in[8];
    const float* gamma  = (const float*)d_in[9];
    const float* beta   = (const float*)d_in[10];
    const float* hw     = (const float*)d_in[11];
    const float* hb     = (const float*)d_in[12];
    float* logits = (float*)d_out;

    char* ws = (char*)d_ws;
    unsigned short* feats = (unsigned short*)(ws);
    unsigned short* kpwS  = (unsigned short*)(ws + WS_KPWT);
    float* outbuf = (float*)(ws + WS_OUT);
    float* stats  = (float*)(ws + WS_STATS);

    hipLaunchKernelGGL(gs_kernel,     dim3(20000), dim3(256), 0, stream, x, px, py, feats);
    hipLaunchKernelGGL(wt_kernel,     dim3(3840),  dim3(256), 0, stream, kpw, kpwS, stats);
    hipLaunchKernelGGL(kpconv_kernel, dim3(5024),  dim3(64),  0, stream,
                       feats, kpwS, pknn, pxyz, kp_pts, outbuf, stats);
    hipLaunchKernelGGL(head_kernel,   dim3(5000),  dim3(256), 0, stream,
                       outbuf, stats, gamma, beta, hw, hb, logits);
}